// Round 9
// baseline (5670.432 us; speedup 1.0000x reference)
//
#include <hip/hip_runtime.h>

#define T_STEPS 8192
#define BATCH   128
#define HID     128
#define NTHR    256               // 4 waves, 1 per SIMD; SPLIT=2 over k

typedef float v2f __attribute__((ext_vector_type(2)));

// tanh(z) = sign(z) * (1 - e^{-2|z|}) / (1 + e^{-2|z|})  -- no overflow path
__device__ __forceinline__ float fast_tanh(float z) {
    float az = fabsf(z);
    float e  = __expf(-2.0f * az);
    float r  = __fdividef(1.0f - e, 1.0f + e);
    return copysignf(r, z);
}

// wave64 sum via DPP (VALU-only, 6 dependent adds), broadcast from lane 63.
__device__ __forceinline__ float wave64_sum(float x) {
#define DPP_ADD(ctrl) do {                                                        \
        int t_ = __builtin_amdgcn_update_dpp(0, __builtin_bit_cast(int, x),       \
                                             (ctrl), 0xf, 0xf, false);            \
        x += __builtin_bit_cast(float, t_); } while (0)
    DPP_ADD(0x111); DPP_ADD(0x112); DPP_ADD(0x114);
    DPP_ADD(0x118); DPP_ADD(0x142); DPP_ADD(0x143);
#undef DPP_ADD
    int s_ = __builtin_amdgcn_readlane(__builtin_bit_cast(int, x), 63);
    return __builtin_bit_cast(float, s_);
}

__device__ __forceinline__ float bcast_lane(float v, int l) {
    int r = __builtin_amdgcn_readlane(__builtin_bit_cast(int, v), l);
    return __builtin_bit_cast(float, r);
}

// R9: R8's one-barrier skeleton, issue-minimized (R8 counters: VALUBusy 2x at
// flat dur -> issue-bound on redundant work). 4 waves (1/SIMD, no issue-port
// sharing), v_pk_fma_f32 (64 MACs -> 32 instrs), h1 via wave-private LDS
// broadcast (readlane path retired: 64 instrs -> 16 ds + 32 pk_fma).
__global__ __launch_bounds__(NTHR, 1) void odenet_scan(
    const float* __restrict__ x,
    const float* __restrict__ W1, const float* __restrict__ b1,
    const float* __restrict__ W2, const float* __restrict__ b2,
    const float* __restrict__ W3, const float* __restrict__ b3,
    float* __restrict__ out) {

    const int b    = blockIdx.x;        // batch element
    const int tid  = threadIdx.x;
    const int w    = tid >> 6;          // wave 0..3
    const int s    = tid >> 7;          // k-split 0..1 (uniform per wave)
    const int j    = tid & (HID - 1);   // output hidden unit 0..127
    const int lane = tid & 63;
    const int k1   = (s << 6) | lane;   // h1 unit this lane computes

    __shared__ __align__(16) float h1w[4][64];     // wave-private h1 regions
    __shared__ __align__(16) float pbuf[2][NTHR];  // [parity][s*128 + j]

    // ---- W2 fragment: rows [64s, 64s+64) of column j, packed as 32 v2f ----
    const float* col = W2 + j;          // column j, row stride HID
    const int kb = s << 6;
#define FORALL16(M) M(0) M(1) M(2) M(3) M(4) M(5) M(6) M(7) \
                    M(8) M(9) M(10) M(11) M(12) M(13) M(14) M(15)
#define DECLW(i) v2f wpA##i = {col[(kb + 4*(i) + 0) * HID],                       \
                               col[(kb + 4*(i) + 1) * HID]},                      \
                     wpB##i = {col[(kb + 4*(i) + 2) * HID],                       \
                               col[(kb + 4*(i) + 3) * HID]};
    FORALL16(DECLW)
#undef DECLW
#define PINW(i) asm volatile("" : "+v"(wpA##i), "+v"(wpB##i));
    FORALL16(PINW)
#undef PINW

    float w1xk = W1[k1], w1yk = W1[HID + k1], b1k = b1[k1];
    float b2a = b2[lane], b2b = b2[lane + 64];
    float w3a = W3[lane], w3b = W3[lane + 64];
    float b3v = b3[0];
    asm volatile("" : "+v"(w1xk), "+v"(w1yk), "+v"(b1k), "+v"(b2a), "+v"(b2b),
                      "+v"(w3a), "+v"(w3b), "+v"(b3v));

    float y    = 0.0f;
    float xbuf = 0.0f;   // per wave: lane l holds x[(tblk+l)*B + b]
    float ybuf = 0.0f;   // wave 0: lane l holds y_{tblk+l+1}
    if (tid == 0) out[b] = 0.0f;        // y_0 = 0

    const float4* h4 = (const float4*)h1w[w];

    for (int t = 0; t < T_STEPS - 1; ++t) {
        const int tm = t & 63;
        if (tm == 0)                                // one x block per 64 steps
            xbuf = x[(t + lane) * BATCH + b];       // same addrs all waves (L1)
        float xv = bcast_lane(xbuf, tm);            // uniform (SGPR)

        // ---- layer 1: lane computes h1[k1]; wave-private LDS round-trip,
        // same-wave RAW -> lgkmcnt only, NO barrier
        h1w[w][lane] = fast_tanh(fmaf(xv, w1xk, fmaf(y, w1yk, b1k)));

        // ---- layer 2 partial: 16 broadcast ds_read_b128 + 32 v_pk_fma_f32
        v2f acc0 = {0.f, 0.f}, acc1 = {0.f, 0.f};
        v2f acc2 = {0.f, 0.f}, acc3 = {0.f, 0.f};
#define FMAQ(i) { float4 q = h4[i];                                               \
        v2f hlo = {q.x, q.y}, hhi = {q.z, q.w};                                   \
        if ((i) & 1) { acc2 += wpA##i * hlo; acc3 += wpB##i * hhi; }              \
        else         { acc0 += wpA##i * hlo; acc1 += wpB##i * hhi; } }
        FORALL16(FMAQ)
#undef FMAQ
        v2f accp = (acc0 + acc1) + (acc2 + acc3);
        pbuf[t & 1][(s << 7) | j] = accp.x + accp.y;

        __syncthreads();   // the ONLY barrier: cross-s partials visible

        // ---- phase C, redundant in all 4 waves (bit-identical) ----
        const float* pb = pbuf[t & 1];
        float sa = pb[lane]      + pb[lane + 128];   // unit lane
        float sb = pb[lane + 64] + pb[lane + 192];   // unit lane+64
        float c = fmaf(w3a, fast_tanh(sa + b2a), w3b * fast_tanh(sb + b2b));
        y += wave64_sum(c) + b3v;                    // DT = 1.0

        // capture + batched store (wave 0 only; wave-uniform branch)
        if (tid < 64) {
            ybuf = (lane == tm) ? y : ybuf;
            if (tm == 63)
                out[(t - 62 + lane) * BATCH + b] = ybuf;
        }
    }
    // tail: t=8128..8190 captured y_8129..y_8191 in lanes 0..62 of wave 0
    if (tid < 63)
        out[(T_STEPS - 63 + lane) * BATCH + b] = ybuf;
}

extern "C" void kernel_launch(void* const* d_in, const int* in_sizes, int n_in,
                              void* d_out, int out_size, void* d_ws, size_t ws_size,
                              hipStream_t stream) {
    const float* x  = (const float*)d_in[0];
    const float* W1 = (const float*)d_in[1];
    const float* b1 = (const float*)d_in[2];
    const float* W2 = (const float*)d_in[3];
    const float* b2 = (const float*)d_in[4];
    const float* W3 = (const float*)d_in[5];
    const float* b3 = (const float*)d_in[6];

    odenet_scan<<<dim3(BATCH), dim3(NTHR), 0, stream>>>(
        x, W1, b1, W2, b2, W3, b3, (float*)d_out);
}

// Round 10
// 4762.769 us; speedup vs baseline: 1.1906x; 1.1906x over previous
//
#include <hip/hip_runtime.h>

#define T_STEPS 8192
#define BATCH   128
#define HID     128
#define NTHR    512               // 8 waves, 2/SIMD (R8-proven latency hiding)

typedef float v2f __attribute__((ext_vector_type(2)));

// tanh(z) = sign(z) * (1 - e^{-2|z|}) / (1 + e^{-2|z|})  -- no overflow path
__device__ __forceinline__ float fast_tanh(float z) {
    float az = fabsf(z);
    float e  = __expf(-2.0f * az);
    float r  = __fdividef(1.0f - e, 1.0f + e);
    return copysignf(r, z);
}

// wave64 sum via DPP (VALU-only, 6 dependent adds), broadcast from lane 63.
__device__ __forceinline__ float wave64_sum(float x) {
#define DPP_ADD(ctrl) do {                                                        \
        int t_ = __builtin_amdgcn_update_dpp(0, __builtin_bit_cast(int, x),       \
                                             (ctrl), 0xf, 0xf, false);            \
        x += __builtin_bit_cast(float, t_); } while (0)
    DPP_ADD(0x111); DPP_ADD(0x112); DPP_ADD(0x114);
    DPP_ADD(0x118); DPP_ADD(0x142); DPP_ADD(0x143);
#undef DPP_ADD
    int s_ = __builtin_amdgcn_readlane(__builtin_bit_cast(int, x), 63);
    return __builtin_bit_cast(float, s_);
}

__device__ __forceinline__ float bcast_lane(float v, int l) {
    int r = __builtin_amdgcn_readlane(__builtin_bit_cast(int, v), l);
    return __builtin_bit_cast(float, r);
}

#define FORALL16(M) M(0) M(1) M(2) M(3) M(4) M(5) M(6) M(7) \
                    M(8) M(9) M(10) M(11) M(12) M(13) M(14) M(15)

// R10 = R8 skeleton (8 waves / SPLIT=4 / ONE barrier / parity pbuf / redundant
// phase C) with the chain issue-minimized:
//  - phase B: wave-PRIVATE h1 LDS copy (no cross-wave dep, no barrier) + 8
//    broadcast ds_read_b128 + 16 v_pk_fma_f32  (was: 32 readlane + 32 fmaf)
//  - phase C: transposed pbuf [j*4+perm], perm=(s+(j>>3))&3 -> writes <=2-way
//    (free, m136), reads = 2 stride-1 ds_read_b128  (was: 8 ds_read_b32)
// R8/R9 counter pair proved latency-bound + 2-waves/SIMD hiding; this cuts
// issue/SIMD ~536 -> ~300 cyc without adding cross-wave sync.
__global__ __launch_bounds__(NTHR, 2) void odenet_scan(
    const float* __restrict__ x,
    const float* __restrict__ W1, const float* __restrict__ b1,
    const float* __restrict__ W2, const float* __restrict__ b2,
    const float* __restrict__ W3, const float* __restrict__ b3,
    float* __restrict__ out) {

    const int b    = blockIdx.x;        // batch element
    const int tid  = threadIdx.x;
    const int w    = tid >> 6;          // wave 0..7
    const int s    = tid >> 7;          // k-split 0..3 (uniform per wave-pair)
    const int j    = tid & (HID - 1);   // output hidden unit 0..127
    const int lane = tid & 63;
    const int k1   = (s << 5) | (lane & 31);   // h1 unit this lane computes

    __shared__ __align__(16) float h1w[8][32];     // wave-private h1 copies
    __shared__ __align__(16) float pbuf[2][4 * HID];  // [parity][j*4 + perm]

    // ---- W2 fragment: rows [32s, 32s+32) of column j, packed as 16 v2f ----
    const float* col = W2 + j;          // column j, row stride HID
    const int kb = s << 5;
#define DECLW(i) v2f wp##i = {col[(kb + 2*(i) + 0) * HID],                        \
                              col[(kb + 2*(i) + 1) * HID]};
    FORALL16(DECLW)
#undef DECLW
#define PINW(i) asm volatile("" : "+v"(wp##i));
    FORALL16(PINW)
#undef PINW

    float w1xk = W1[k1], w1yk = W1[HID + k1], b1k = b1[k1];
    float b2a = b2[lane], b2b = b2[lane + 64];
    float w3a = W3[lane], w3b = W3[lane + 64];
    float b3v = b3[0];
    asm volatile("" : "+v"(w1xk), "+v"(w1yk), "+v"(b1k), "+v"(b2a), "+v"(b2b),
                      "+v"(w3a), "+v"(w3b), "+v"(b3v));

    const int pstore = (j << 2) | ((s + (j >> 3)) & 3);  // rotated transpose
    const float4* h4 = (const float4*)h1w[w];

    float y    = 0.0f;
    float xbuf = 0.0f;   // per wave: lane l holds x[(tblk+l)*B + b]
    float ybuf = 0.0f;   // wave 0: lane l holds y_{tblk+l+1}
    if (tid == 0) out[b] = 0.0f;        // y_0 = 0

    for (int t = 0; t < T_STEPS - 1; ++t) {
        const int tm = t & 63;
        if (tm == 0)                                // one x block per 64 steps
            xbuf = x[(t + lane) * BATCH + b];       // same addrs all waves (L1)
        float xv = bcast_lane(xbuf, tm);            // uniform (SGPR)

        // ---- layer 1: lane computes h1[k1] -> OWN wave's LDS region.
        // Lanes l and l+32 write the same addr with the same value (benign).
        // Same-wave RAW only -> lgkmcnt, NO barrier.
        h1w[w][lane & 31] = fast_tanh(fmaf(xv, w1xk, fmaf(y, w1yk, b1k)));

        // ---- layer 2 partial: 8 broadcast b128 reads + 16 v_pk_fma_f32 ----
        v2f acc0 = {0.f, 0.f}, acc1 = {0.f, 0.f};
        v2f acc2 = {0.f, 0.f}, acc3 = {0.f, 0.f};
#define FMAQ(q_, ilo, ihi) { float4 q = (q_);                                     \
        v2f hlo = {q.x, q.y}, hhi = {q.z, q.w};                                   \
        acc##ilo += wp##ilo * hlo;  acc##ihi hhi_use                              \
        }
#undef FMAQ
        {
            float4 q0 = h4[0], q1 = h4[1], q2 = h4[2], q3 = h4[3];
            float4 q4 = h4[4], q5 = h4[5], q6 = h4[6], q7 = h4[7];
            v2f h0 = {q0.x, q0.y}, h1_ = {q0.z, q0.w};
            v2f h2 = {q1.x, q1.y}, h3 = {q1.z, q1.w};
            v2f h4v = {q2.x, q2.y}, h5 = {q2.z, q2.w};
            v2f h6 = {q3.x, q3.y}, h7 = {q3.z, q3.w};
            v2f h8 = {q4.x, q4.y}, h9 = {q4.z, q4.w};
            v2f h10 = {q5.x, q5.y}, h11 = {q5.z, q5.w};
            v2f h12 = {q6.x, q6.y}, h13 = {q6.z, q6.w};
            v2f h14 = {q7.x, q7.y}, h15 = {q7.z, q7.w};
            acc0 += wp0 * h0;   acc1 += wp1 * h1_;
            acc2 += wp2 * h2;   acc3 += wp3 * h3;
            acc0 += wp4 * h4v;  acc1 += wp5 * h5;
            acc2 += wp6 * h6;   acc3 += wp7 * h7;
            acc0 += wp8 * h8;   acc1 += wp9 * h9;
            acc2 += wp10 * h10; acc3 += wp11 * h11;
            acc0 += wp12 * h12; acc1 += wp13 * h13;
            acc2 += wp14 * h14; acc3 += wp15 * h15;
        }
        v2f accp = (acc0 + acc1) + (acc2 + acc3);
        pbuf[t & 1][pstore] = accp.x + accp.y;

        __syncthreads();   // the ONLY barrier: cross-wave partials visible

        // ---- phase C, redundant in all 8 waves (bit-identical) ----
        const float4* pb4 = (const float4*)pbuf[t & 1];
        float4 qa = pb4[lane];        // 4 partials of unit lane (permuted)
        float4 qb = pb4[lane + 64];   // 4 partials of unit lane+64
        float sa = (qa.x + qa.y) + (qa.z + qa.w);
        float sb = (qb.x + qb.y) + (qb.z + qb.w);
        float c = fmaf(w3a, fast_tanh(sa + b2a), w3b * fast_tanh(sb + b2b));
        y += wave64_sum(c) + b3v;                    // DT = 1.0

        // capture + batched store (wave 0 only; wave-uniform branch)
        if (tid < 64) {
            ybuf = (lane == tm) ? y : ybuf;
            if (tm == 63)
                out[(t - 62 + lane) * BATCH + b] = ybuf;
        }
    }
    // tail: t=8128..8190 captured y_8129..y_8191 in lanes 0..62 of wave 0
    if (tid < 63)
        out[(T_STEPS - 63 + lane) * BATCH + b] = ybuf;
}

extern "C" void kernel_launch(void* const* d_in, const int* in_sizes, int n_in,
                              void* d_out, int out_size, void* d_ws, size_t ws_size,
                              hipStream_t stream) {
    const float* x  = (const float*)d_in[0];
    const float* W1 = (const float*)d_in[1];
    const float* b1 = (const float*)d_in[2];
    const float* W2 = (const float*)d_in[3];
    const float* b2 = (const float*)d_in[4];
    const float* W3 = (const float*)d_in[5];
    const float* b3 = (const float*)d_in[6];

    odenet_scan<<<dim3(BATCH), dim3(NTHR), 0, stream>>>(
        x, W1, b1, W2, b2, W3, b3, (float*)d_out);
}